// Round 1
// baseline (139.561 us; speedup 1.0000x reference)
//
#include <hip/hip_runtime.h>

// RoutingMaskLayer: out[b,h,w,j] = in[b,h,w, argmax(routing[b,:])*RW + j]
// Shapes: in [32,56,56,256] f32, routing [32,4] f32, out [32,56,56,64] f32.
//
// Traffic model: selected channels form a contiguous 256B-aligned block per
// pixel -> minimal HBM traffic = 25.7 MB read + 25.7 MB write ~= 8 us at
// 6.3 TB/s. Prior 140.9 us is ~17x above that => latency/overhead-bound,
// not BW-bound. This version:
//   * block-uniform sample index (49 blocks per sample exactly) -> routing
//     argmax computed once per block in SGPRs (s_load), zero per-thread
//     routing traffic;
//   * 4 independent float4 loads per thread (64 B) issued back-to-back,
//     then 4 stores -> 4-deep memory-level parallelism per lane;
//   * perfect per-instruction coalescing retained (each wave touches a
//     contiguous 1 KB span per iteration).

#define NB 32
#define NH 56
#define NW 56
#define NC 256
#define NROUTES 4
#define RW (NC / NROUTES)                 // 64 channels selected per sample
#define PIX_F4 (RW / 4)                   // 16 float4 per output pixel
#define TOTAL_F4 (NB * NH * NW * PIX_F4)  // 1,605,632
#define F4_PER_BLOCK 1024                 // 4 float4 per thread, 256 threads
#define BLOCKS_PER_B ((NH * NW * PIX_F4) / F4_PER_BLOCK)  // 50176/1024 = 49

__global__ __launch_bounds__(256) void
RoutingMaskLayer_51453708206705_kernel(const float4* __restrict__ in,
                                       const float* __restrict__ routing,
                                       float4* __restrict__ out) {
    // b is uniform across the block: compiler keeps this entirely in SGPRs.
    const int b = blockIdx.x / BLOCKS_PER_B;

    // argmax over the 4 routing logits, first-max tie-break (jnp.argmax).
    // Uniform address -> s_load_dwordx4; argmax runs on the scalar ALU.
    const float* r = routing + b * NROUTES;
    float r0 = r[0], r1 = r[1], r2 = r[2], r3 = r[3];
    int route = 0; float best = r0;
    if (r1 > best) { best = r1; route = 1; }
    if (r2 > best) { best = r2; route = 2; }
    if (r3 > best) { best = r3; route = 3; }
    route = __builtin_amdgcn_readfirstlane(route);  // pin to SGPR

    // Each block owns a contiguous span of 1024 output float4s.
    const int base = blockIdx.x * F4_PER_BLOCK + threadIdx.x;
    const int rbase = route * PIX_F4;

    float4 v[4];
#pragma unroll
    for (int k = 0; k < 4; ++k) {
        const int i   = base + k * 256;   // output float4 index
        const int pix = i >> 4;           // (b,h,w) pixel
        const int j4  = i & 15;           // float4 within the 64-ch block
        // input pixel stride = 256 floats = 64 float4
        v[k] = in[pix * (NC / 4) + rbase + j4];
    }
#pragma unroll
    for (int k = 0; k < 4; ++k) {
        out[base + k * 256] = v[k];
    }
}

extern "C" void kernel_launch(void* const* d_in, const int* in_sizes, int n_in,
                              void* d_out, int out_size, void* d_ws, size_t ws_size,
                              hipStream_t stream) {
    const float4* in      = (const float4*)d_in[0];
    const float*  routing = (const float*)d_in[1];
    float4*       out     = (float4*)d_out;

    constexpr int block = 256;
    constexpr int grid  = TOTAL_F4 / F4_PER_BLOCK;  // 1568, exact
    RoutingMaskLayer_51453708206705_kernel<<<grid, block, 0, stream>>>(in, routing, out);
}

// Round 3
// 135.818 us; speedup vs baseline: 1.0276x; 1.0276x over previous
//
#include <hip/hip_runtime.h>

// RoutingMaskLayer: out[b,h,w,j] = in[b,h,w, argmax(routing[b,:])*RW + j]
// Shapes: in [32,56,56,256] f32, routing [32,4] f32, out [32,56,56,64] f32.
//
// Round-1 finding: reported dur_us (~139.6) includes ~2 harness re-poison
// fills (~62 us each, 83% HBM peak, 411 MB) that dominate; the kernel itself
// is ~14.5 us (51.4 MB minimal traffic at ~3.5 TB/s). This round: deepen MLP
// (8 float4 per thread, all loads issued before stores) + nontemporal hints
// on both touch-once streams.
// Round-2 fix: __builtin_nontemporal_* requires native vector types, not
// HIP_vector_type<float,4> -> use ext_vector_type(4).

#define NB 32
#define NH 56
#define NW 56
#define NC 256
#define NROUTES 4
#define RW (NC / NROUTES)                 // 64 channels selected per sample
#define PIX_F4 (RW / 4)                   // 16 float4 per output pixel
#define TOTAL_F4 (NB * NH * NW * PIX_F4)  // 1,605,632
#define F4_PER_CHUNK 1024                 // 4 float4 per thread, 256 threads
#define CHUNKS (TOTAL_F4 / F4_PER_CHUNK)  // 1568
#define CHUNKS_PER_B ((NH * NW * PIX_F4) / F4_PER_CHUNK)  // 49, exact
#define GRID (CHUNKS / 2)                 // 784 blocks, 2 chunks each

typedef float f4 __attribute__((ext_vector_type(4)));  // native vector: ok for nontemporal builtins

__device__ __forceinline__ int route_of(const float* __restrict__ routing, int b) {
    // Uniform address -> s_load; argmax with first-max tie-break (jnp.argmax).
    const float* r = routing + b * NROUTES;
    float r0 = r[0], r1 = r[1], r2 = r[2], r3 = r[3];
    int route = 0; float best = r0;
    if (r1 > best) { best = r1; route = 1; }
    if (r2 > best) { best = r2; route = 2; }
    if (r3 > best) { best = r3; route = 3; }
    return __builtin_amdgcn_readfirstlane(route);
}

__global__ __launch_bounds__(256) void
RoutingMaskLayer_51453708206705_kernel(const f4* __restrict__ in,
                                       const float* __restrict__ routing,
                                       f4* __restrict__ out) {
    // Two 1024-float4 chunks per block; each chunk lies entirely within one
    // sample (1024 | 50176), so b is uniform per chunk -> scalar argmax.
    const int c0 = blockIdx.x;
    const int c1 = blockIdx.x + GRID;

    const int b0 = c0 / CHUNKS_PER_B;     // uniform: scalar magic-mul
    const int b1 = c1 / CHUNKS_PER_B;
    const int rb0 = route_of(routing, b0) * PIX_F4;
    const int rb1 = route_of(routing, b1) * PIX_F4;

    const int base0 = c0 * F4_PER_CHUNK + threadIdx.x;
    const int base1 = c1 * F4_PER_CHUNK + threadIdx.x;

    f4 v0[4], v1[4];
    // Issue all 8 independent loads before any store: 8-deep MLP per lane,
    // each wave-load covers a contiguous 1 KB span (perfect coalescing).
#pragma unroll
    for (int k = 0; k < 4; ++k) {
        const int i = base0 + k * 256;
        v0[k] = __builtin_nontemporal_load(&in[(i >> 4) * (NC / 4) + rb0 + (i & 15)]);
    }
#pragma unroll
    for (int k = 0; k < 4; ++k) {
        const int i = base1 + k * 256;
        v1[k] = __builtin_nontemporal_load(&in[(i >> 4) * (NC / 4) + rb1 + (i & 15)]);
    }
#pragma unroll
    for (int k = 0; k < 4; ++k)
        __builtin_nontemporal_store(v0[k], &out[base0 + k * 256]);
#pragma unroll
    for (int k = 0; k < 4; ++k)
        __builtin_nontemporal_store(v1[k], &out[base1 + k * 256]);
}

extern "C" void kernel_launch(void* const* d_in, const int* in_sizes, int n_in,
                              void* d_out, int out_size, void* d_ws, size_t ws_size,
                              hipStream_t stream) {
    const f4*    in      = (const f4*)d_in[0];
    const float* routing = (const float*)d_in[1];
    f4*          out     = (f4*)d_out;

    constexpr int block = 256;
    RoutingMaskLayer_51453708206705_kernel<<<GRID, block, 0, stream>>>(in, routing, out);
}